// Round 14
// baseline (273.268 us; speedup 1.0000x reference)
//
#include <hip/hip_runtime.h>
#include <hip/hip_fp16.h>
#include <math.h>

#define N_NODES 50000
#define N_EDGES 1600000
#define D_INF   128
#define D_HID   64
#define BN_EPS  1e-5f
#define NBINS   256      // R10: 256 balanced bins (1 binB block per CU)
#define NPB     196      // nodes per bin (256*196 = 50176 >= N)
#define BINCAP  6912     // per-bin cap (mean 6250, +8.4 sigma)
#define EPB     6250     // edges per binA block (256 blocks x 6250 = E)
#define GEMM1B  3125     // gemm1 blocks inside k_pre
#define NPAIR   3125     // gather block-pairs (16 nodes each)
#define NCOPY   64       // BN stat accumulator copies (atomic spread)

// ============ fused k_pre: blocks 0..255 binA | 256..3380 gemm1 ============
// Ledger: reserved-contiguous-run binned writes are the density optimum
// (R4: direct scatter = 8x XCD write amp; R6: small bins = partial lines;
// R9: fixed slices = cross-XCD false sharing; R10: 196-node bins -> 195B
// runs, WRITE 27MB, best). R5: no grid.sync mega (phase regalloc + L2
// flush). R8: random-address device atomics cost ~32B HBM each.
// R11: TA dedups clamped same-address wave-gather lanes (guards ~free).
// R12: binB is LDS-op-throughput bound (1024-thr TLP null) AND the
// 1024-thr variant failed replay correctness -- binB stays at 512.
struct SmGemm { float sw[D_INF * D_HID]; float sx[16 * D_INF]; };  // 40 KB
struct SmBin  { int hcnt[NBINS]; int hbase[NBINS]; };              // 2 KB
union SmPre { SmGemm g; SmBin a; };

__global__ __launch_bounds__(256) void k_pre(const float* __restrict__ wsc,
                                             const float* __restrict__ wfc,
                                             const int*   __restrict__ ei,
                                             const float* __restrict__ alpha,
                                             int* __restrict__ bin_cur,
                                             unsigned long long* __restrict__ binned,
                                             const float* __restrict__ x,
                                             const float* __restrict__ W,
                                             __half* __restrict__ ha,
                                             __half* __restrict__ hb) {
    __shared__ SmPre sm;
    int t = threadIdx.x;
    if (blockIdx.x < 256) {
        // ---------------- binA: bin edges by dst/196, staged coalesced -----
        int e0 = blockIdx.x * EPB;
        sm.a.hcnt[t] = 0;
        __syncthreads();
        for (int i = t; i < EPB; i += 256)
            atomicAdd(&sm.a.hcnt[(unsigned)ei[N_EDGES + e0 + i] / NPB], 1);
        __syncthreads();
        {
            int c = sm.a.hcnt[t];
            sm.a.hbase[t] = c ? atomicAdd(&bin_cur[t], c) : 0;
            sm.a.hcnt[t] = 0;
        }
        __syncthreads();
        float a = 1.0f / (1.0f + expf(-alpha[0]));
        for (int i = t; i < EPB; i += 256) {
            int e = e0 + i;
            int s = ei[e], d = ei[N_EDGES + e];
            float wm = fmaf(a, wsc[e] - wfc[e], wfc[e]);   // a*wsc+(1-a)*wfc
            int bin = (unsigned)d / NPB;
            int loc = d - bin * NPB;                       // 0..195, 8 bits
            int slot = atomicAdd(&sm.a.hcnt[bin], 1);
            int gpos = sm.a.hbase[bin] + slot;
            if (gpos < BINCAP) {
                unsigned long long ent =
                    ((unsigned long long)__float_as_uint(wm) << 32)
                    | (unsigned int)(s | (loc << 16));
                binned[(size_t)bin * BINCAP + gpos] = ent;
            }
        }
    } else {
        // ---------------- gemm1: [N,128]x[128,64] -> fp16 halves -----------
        int row0 = (blockIdx.x - 256) * 16;
#pragma unroll
        for (int j = 0; j < 32; ++j) sm.g.sw[t + j * 256] = W[t + j * 256];
#pragma unroll
        for (int j = 0; j < 8; ++j) {
            int i = t + j * 256;
            int r = i >> 7, k = i & 127;
            sm.g.sx[i] = x[(row0 + r) * D_INF + k];
        }
        __syncthreads();
        int c = t & 63, rg = (t >> 6) * 4;
        float a0 = 0, a1 = 0, a2 = 0, a3 = 0;
#pragma unroll 4
        for (int k = 0; k < D_INF; ++k) {
            float w = sm.g.sw[k * D_HID + c];
            a0 = fmaf(sm.g.sx[(rg + 0) * D_INF + k], w, a0);
            a1 = fmaf(sm.g.sx[(rg + 1) * D_INF + k], w, a1);
            a2 = fmaf(sm.g.sx[(rg + 2) * D_INF + k], w, a2);
            a3 = fmaf(sm.g.sx[(rg + 3) * D_INF + k], w, a3);
        }
        __half* tbl = (c < 32) ? ha : hb;
        int cc = c & 31;
        tbl[(row0 + rg + 0) * 32 + cc] = __float2half_rn(a0);
        tbl[(row0 + rg + 1) * 32 + cc] = __float2half_rn(a1);
        tbl[(row0 + rg + 2) * 32 + cc] = __float2half_rn(a2);
        tbl[(row0 + rg + 3) * 32 + cc] = __float2half_rn(a3);
    }
}

// ====== merged phase B (512 thr, 256 balanced blocks = 1/CU): LDS-stage
// entries once; packed-u64 hist -> dinv, row_se; scale h by dinv; fill csr.
// R7's one-atomic pass-1 (count<<48 | wm in 2^-32 fixed point; max
// 6912*2^32 = 2^44.8 < 2^48; ~1e-8 deg quantization). LDS ~60 KB.
// 512 threads: R12's 1024-thr variant was perf-null (LDS-op throughput
// bound) and failed replay correctness -- do not revisit.
__global__ __launch_bounds__(512) void k_binB(const int* __restrict__ bin_cur,
                                              const unsigned long long* __restrict__ binned,
                                              int2*  __restrict__ row_se,
                                              float* __restrict__ dinv,
                                              __half* __restrict__ ha,
                                              __half* __restrict__ hb,
                                              unsigned int* __restrict__ csr) {
    __shared__ unsigned long long stage[BINCAP];   // 55.3 KB
    __shared__ unsigned long long nacc[256];       // count<<48 | fixed ndeg
    __shared__ int   ncnt[256];
    __shared__ int   sscan[256];
    __shared__ float sdinv[256];
    __shared__ int   lb[256];
    int t = threadIdx.x;
    int bin = blockIdx.x;
    if (t < 256) nacc[t] = 0ULL;
    int cnt = min(bin_cur[bin], BINCAP);
    const unsigned long long* mybin = binned + (size_t)bin * BINCAP;
    for (int i = t; i < cnt; i += 512) stage[i] = mybin[i];
    __syncthreads();
    for (int i = t; i < cnt; i += 512) {
        unsigned long long ent = stage[i];
        unsigned int lo = (unsigned int)ent;
        int nl = (lo >> 16) & 255;
        float wm = __uint_as_float((unsigned int)(ent >> 32));
        unsigned long long pk = (1ULL << 48)
            | (unsigned long long)(wm * 4294967296.0f);
        atomicAdd(&nacc[nl], pk);
    }
    __syncthreads();
    int node0 = bin * NPB;
    int nnodes = min(NPB, N_NODES - node0);
    if (t < 256) {
        unsigned long long v = nacc[t];
        int c = (int)(v >> 48);
        float nd = (float)(v & 0xFFFFFFFFFFFFULL) * 2.3283064365386963e-10f;
        float dv = rsqrtf(1.0f + nd);   // +1 self loop
        sdinv[t] = dv;
        if (t < nnodes) dinv[node0 + t] = dv;
        ncnt[t] = c;
        sscan[t] = c;
    }
    __syncthreads();
    for (int off = 1; off < 256; off <<= 1) {
        int u = (t >= off && t < 256) ? sscan[t - off] : 0;
        __syncthreads();
        if (t < 256) sscan[t] += u;
        __syncthreads();
    }
    if (t < nnodes) {
        int lbt = sscan[t] - ncnt[t];
        int s = bin * BINCAP + lbt;
        row_se[node0 + t] = make_int2(s, s + ncnt[t]);
    }
    if (t < 256) lb[t] = sscan[t] - ncnt[t];
    __syncthreads();
    // scale this bin's h rows by dinv (vectorized __half2, 4 B/lane)
    int nh = nnodes * 16;   // 16 half2 per table row
    __half2* pa = (__half2*)ha;
    __half2* pb = (__half2*)hb;
    for (int i = t; i < nh; i += 512) {
        int n = i >> 4;
        float dv = sdinv[n];
        int idx = node0 * 16 + i;
        float2 fa = __half22float2(pa[idx]);
        float2 fb = __half22float2(pb[idx]);
        pa[idx] = __floats2half2_rn(fa.x * dv, fa.y * dv);
        pb[idx] = __floats2half2_rn(fb.x * dv, fb.y * dv);
    }
    if (t < 256) ncnt[t] = 0;   // reuse as fill cursor
    __syncthreads();
    for (int i = t; i < cnt; i += 512) {
        unsigned long long ent = stage[i];
        unsigned int lo = (unsigned int)ent;
        int nl  = (lo >> 16) & 255;
        int src = lo & 0xFFFFu;
        float wm = __uint_as_float((unsigned int)(ent >> 32));
        int slot = atomicAdd(&ncnt[nl], 1);
        unsigned short wh = __half_as_ushort(__float2half_rn(wm));
        csr[bin * BINCAP + lb[nl] + slot] =
            (unsigned int)src | ((unsigned int)wh << 16);
    }
}

__device__ inline float hdec(unsigned int u) {
    return __half2float(__ushort_as_half((unsigned short)(u >> 16)));
}

// == gather (512 thr): WIDE 16B/lane table reads (R3: 123->38us) + R11
// guarded batch steps (free; TA dedups clamped lanes anyway). TA
// address-throughput bound; 16B/lane is the width limit.
// BN stats: block LDS reduce -> atomics spread over NCOPY copies (R1 law).
// out[d] = dd * ( sum_e wm_e * h'[s_e] + h'[d] ) + bias   (h' = dinv*h)
__global__ __launch_bounds__(512) void k_gather(const __half* __restrict__ ha,
                                                const __half* __restrict__ hb,
                                                const unsigned int* __restrict__ csr,
                                                const int2*  __restrict__ row_se,
                                                const float* __restrict__ dinv,
                                                const float* __restrict__ bias,
                                                float* __restrict__ out,
                                                float* __restrict__ stat) {
    __shared__ float s1[512], s2[512];
    int t = threadIdx.x;
    int half = blockIdx.x & 1;
    const float4* __restrict__ h4 = (const float4*)(half ? hb : ha);
    int node = (blockIdx.x >> 1) * 16 + (t >> 5);
    int ln = t & 31;
    int sg = ln >> 2;     // 0..7: edge subgroup
    int cq = ln & 3;      // 0..3: column quad (8 cols = 16B)
    int2 se = row_se[node];
    float dd = dinv[node];
    float acc[8];
    if (sg == 0) {        // self term (pre-scaled by dinv), added once
        float4 sv = h4[node * 4 + cq];
        const __half2* p = reinterpret_cast<const __half2*>(&sv);
#pragma unroll
        for (int i = 0; i < 4; ++i) {
            float2 f = __half22float2(p[i]);
            acc[2 * i] = f.x; acc[2 * i + 1] = f.y;
        }
    } else {
#pragma unroll
        for (int i = 0; i < 8; ++i) acc[i] = 0.0f;
    }
    for (int b = se.x; b < se.y; b += 32) {
        int c0 = min(32, se.y - b);
        int cm = c0 - 1;
        unsigned int my = (ln < c0) ? csr[b + ln] : 0u;
        float4 r1 = make_float4(0.f, 0.f, 0.f, 0.f);
        float4 r2 = r1, r3 = r1;
        float w1 = 0.f, w2 = 0.f, w3 = 0.f;
        unsigned int u0 = __shfl(my, min(sg, cm), 32);
        float4 r0 = h4[(u0 & 0xFFFFu) * 4 + cq];
        float w0 = (sg < c0) ? hdec(u0) : 0.0f;
        if (c0 > 8) {
            unsigned int u1 = __shfl(my, min(sg + 8, cm), 32);
            r1 = h4[(u1 & 0xFFFFu) * 4 + cq];
            w1 = (sg + 8 < c0) ? hdec(u1) : 0.0f;
        }
        if (c0 > 16) {
            unsigned int u2 = __shfl(my, min(sg + 16, cm), 32);
            r2 = h4[(u2 & 0xFFFFu) * 4 + cq];
            w2 = (sg + 16 < c0) ? hdec(u2) : 0.0f;
        }
        if (c0 > 24) {
            unsigned int u3 = __shfl(my, min(sg + 24, cm), 32);
            r3 = h4[(u3 & 0xFFFFu) * 4 + cq];
            w3 = (sg + 24 < c0) ? hdec(u3) : 0.0f;
        }
        const __half2* p0 = reinterpret_cast<const __half2*>(&r0);
        const __half2* p1 = reinterpret_cast<const __half2*>(&r1);
        const __half2* p2 = reinterpret_cast<const __half2*>(&r2);
        const __half2* p3 = reinterpret_cast<const __half2*>(&r3);
#pragma unroll
        for (int i = 0; i < 4; ++i) {
            float2 f0 = __half22float2(p0[i]);
            float2 f1 = __half22float2(p1[i]);
            float2 f2 = __half22float2(p2[i]);
            float2 f3 = __half22float2(p3[i]);
            acc[2*i]   = fmaf(f0.x, w0, acc[2*i]);
            acc[2*i+1] = fmaf(f0.y, w0, acc[2*i+1]);
            acc[2*i]   = fmaf(f1.x, w1, acc[2*i]);
            acc[2*i+1] = fmaf(f1.y, w1, acc[2*i+1]);
            acc[2*i]   = fmaf(f2.x, w2, acc[2*i]);
            acc[2*i+1] = fmaf(f2.y, w2, acc[2*i+1]);
            acc[2*i]   = fmaf(f3.x, w3, acc[2*i]);
            acc[2*i+1] = fmaf(f3.y, w3, acc[2*i+1]);
        }
    }
    // fold 8 edge-subgroups (stride-4 lanes) -> lanes 0..3 hold 32 cols
#pragma unroll
    for (int off = 16; off >= 4; off >>= 1) {
#pragma unroll
        for (int i = 0; i < 8; ++i) acc[i] += __shfl_down(acc[i], off, 32);
    }
    if (ln < 4) {
        int col0 = half * 32 + cq * 8;
        float v[8];
#pragma unroll
        for (int i = 0; i < 8; ++i) v[i] = fmaf(acc[i], dd, bias[col0 + i]);
        float4* o = (float4*)out;
        o[node * 16 + half * 8 + cq * 2]     = make_float4(v[0], v[1], v[2], v[3]);
        o[node * 16 + half * 8 + cq * 2 + 1] = make_float4(v[4], v[5], v[6], v[7]);
        int lbx = (t >> 5) * 32 + cq * 8;
#pragma unroll
        for (int i = 0; i < 8; ++i) { s1[lbx + i] = v[i]; s2[lbx + i] = v[i] * v[i]; }
    }
    __syncthreads();
#pragma unroll
    for (int off = 256; off >= 32; off >>= 1) {
        if (t < off) { s1[t] += s1[t + off]; s2[t] += s2[t + off]; }
        __syncthreads();
    }
    if (t < 32) {
        int cp = (blockIdx.x >> 1) & (NCOPY - 1);
        int col = half * 32 + t;
        atomicAdd(&stat[cp * 128 + col],      s1[t]);
        atomicAdd(&stat[cp * 128 + 64 + col], s2[t]);
    }
}

// == GEMM2 fused BN1+ReLU in, dinv-scaled split fp16 out: [N,64]x[64,64] ====
// BN scale/shift computed inline from NCOPY-spread stat accumulators.
__global__ __launch_bounds__(256) void k_gemm2_bn(const float* __restrict__ hin,
                                                  const float* __restrict__ stat,
                                                  const float* __restrict__ gamma,
                                                  const float* __restrict__ beta,
                                                  const float* __restrict__ W,
                                                  const float* __restrict__ dinv,
                                                  __half* __restrict__ ha,
                                                  __half* __restrict__ hb) {
    __shared__ float sw[D_HID * D_HID];   // 16 KB
    __shared__ float sx[16 * D_HID];      // 4 KB
    __shared__ float sc[D_HID], sh[D_HID];
    int t = threadIdx.x;
    int row0 = blockIdx.x * 16;
#pragma unroll
    for (int j = 0; j < 16; ++j) sw[t + j * 256] = W[t + j * 256];
    if (t < 64) {
        float s = 0.0f, q = 0.0f;
#pragma unroll 8
        for (int c = 0; c < NCOPY; ++c) {
            s += stat[c * 128 + t];
            q += stat[c * 128 + 64 + t];
        }
        const float invn = 1.0f / (float)N_NODES;
        float mean = s * invn;
        float var  = q * invn - mean * mean;   // biased, = jnp.var
        float g    = gamma[t] * rsqrtf(var + BN_EPS);
        sc[t] = g;
        sh[t] = beta[t] - mean * g;
    }
    __syncthreads();
#pragma unroll
    for (int j = 0; j < 4; ++j) {
        int i = t + j * 256;
        int k = i & 63;
        sx[i] = fmaxf(0.0f, fmaf(hin[row0 * D_HID + i], sc[k], sh[k]));
    }
    __syncthreads();
    int c = t & 63, rg = (t >> 6) * 4;
    float a0 = 0, a1 = 0, a2 = 0, a3 = 0;
#pragma unroll 4
    for (int k = 0; k < D_HID; ++k) {
        float w = sw[k * D_HID + c];
        a0 = fmaf(sx[(rg + 0) * D_HID + k], w, a0);
        a1 = fmaf(sx[(rg + 1) * D_HID + k], w, a1);
        a2 = fmaf(sx[(rg + 2) * D_HID + k], w, a2);
        a3 = fmaf(sx[(rg + 3) * D_HID + k], w, a3);
    }
    __half* tbl = (c < 32) ? ha : hb;
    int cc = c & 31;
    tbl[(row0 + rg + 0) * 32 + cc] = __float2half_rn(a0 * dinv[row0 + rg + 0]);
    tbl[(row0 + rg + 1) * 32 + cc] = __float2half_rn(a1 * dinv[row0 + rg + 1]);
    tbl[(row0 + rg + 2) * 32 + cc] = __float2half_rn(a2 * dinv[row0 + rg + 2]);
    tbl[(row0 + rg + 3) * 32 + cc] = __float2half_rn(a3 * dinv[row0 + rg + 3]);
}

// ====== BN apply + ReLU (in place, float4); coeffs from spread stats =======
__global__ __launch_bounds__(256) void k_bn_apply_relu(float4* __restrict__ h,
                                                       const float* __restrict__ stat,
                                                       const float* __restrict__ gamma,
                                                       const float* __restrict__ beta) {
    __shared__ float sc[D_HID], sh[D_HID];
    int t = threadIdx.x;
    if (t < 64) {
        float s = 0.0f, q = 0.0f;
#pragma unroll 8
        for (int c = 0; c < NCOPY; ++c) {
            s += stat[c * 128 + t];
            q += stat[c * 128 + 64 + t];
        }
        const float invn = 1.0f / (float)N_NODES;
        float mean = s * invn;
        float var  = q * invn - mean * mean;
        float g    = gamma[t] * rsqrtf(var + BN_EPS);
        sc[t] = g;
        sh[t] = beta[t] - mean * g;
    }
    __syncthreads();
    int idx = blockIdx.x * 256 + t;
    if (idx >= N_NODES * D_HID / 4) return;
    int j = (idx & 15) * 4;
    float4 v = h[idx];
    v.x = fmaxf(0.0f, fmaf(v.x, sc[j],     sh[j]));
    v.y = fmaxf(0.0f, fmaf(v.y, sc[j + 1], sh[j + 1]));
    v.z = fmaxf(0.0f, fmaf(v.z, sc[j + 2], sh[j + 2]));
    v.w = fmaxf(0.0f, fmaf(v.w, sc[j + 3], sh[j + 3]));
    h[idx] = v;
}

extern "C" void kernel_launch(void* const* d_in, const int* in_sizes, int n_in,
                              void* d_out, int out_size, void* d_ws, size_t ws_size,
                              hipStream_t stream) {
    const float* x     = (const float*)d_in[0];
    const int*   ei_sc = (const int*)  d_in[1];   // [2*E] src then dst
    const float* w_sc  = (const float*)d_in[2];
    const float* w_fc  = (const float*)d_in[4];
    const float* alpha = (const float*)d_in[5];
    const float* W1    = (const float*)d_in[6];
    const float* b1    = (const float*)d_in[7];
    const float* W2    = (const float*)d_in[8];
    const float* b2    = (const float*)d_in[9];
    const float* g1    = (const float*)d_in[10];
    const float* be1   = (const float*)d_in[11];
    const float* g2    = (const float*)d_in[12];
    const float* be2   = (const float*)d_in[13];
    float* out = (float*)d_out;

    // ---- workspace layout, all segments 16B-aligned: ~40.1 MB
    // binned | row_se | bin_cur(256) | stats | dinv | csr | ha | hb | agg
    unsigned long long* binned = (unsigned long long*)d_ws;        // NBINS*BINCAP u64
    int2*  row_se  = (int2*)(binned + (size_t)NBINS * BINCAP);     // N int2
    int*   bin_cur = (int*)(row_se + N_NODES);                     // 256
    float* stats   = (float*)(bin_cur + NBINS);                    // 2*NCOPY*128
    float* dinv    = stats + 2 * NCOPY * 128;                      // N
    unsigned int* csr = (unsigned int*)(dinv + N_NODES);           // NBINS*BINCAP
    __half* ha     = (__half*)(csr + (size_t)NBINS * BINCAP);      // N*32 halves
    __half* hb     = ha + (size_t)N_NODES * 32;                    // N*32 halves
    float* agg     = (float*)(hb + (size_t)N_NODES * 32);          // N*64

    const int gV4 = (N_NODES * D_HID / 4 + 255) / 256;             // 3125
    const int gGA = NPAIR * 2;                                     // 6250
    const int gGM = N_NODES / 16;                                  // 3125

    // ---- fused binA+gemm1, then balanced CSR build (+dinv fold into h).
    // one memset covers bin_cur AND both layers' spread stat accumulators.
    hipMemsetAsync(bin_cur, 0, (NBINS + 2 * NCOPY * 128) * sizeof(int), stream);
    k_pre <<<256 + GEMM1B, 256, 0, stream>>>(w_sc, w_fc, ei_sc, alpha,
                                             bin_cur, binned, x, W1, ha, hb);
    k_binB<<<NBINS, 512, 0, stream>>>(bin_cur, binned, row_se, dinv, ha, hb, csr);

    // ---- layer 1 (BN stats spread-atomic accumulated in gather epilogue)
    k_gather  <<<gGA, 512, 0, stream>>>(ha, hb, csr, row_se, dinv, b1, agg, stats);

    // ---- layer 2 (BN1+ReLU coeffs computed inline; dinv folded into output)
    k_gemm2_bn<<<gGM, 256, 0, stream>>>(agg, stats, g1, be1, W2, dinv, ha, hb);
    k_gather  <<<gGA, 512, 0, stream>>>(ha, hb, csr, row_se, dinv, b2, out,
                                        stats + NCOPY * 128);
    k_bn_apply_relu<<<gV4, 256, 0, stream>>>((float4*)out, stats + NCOPY * 128,
                                             g2, be2);
}